// Round 2
// baseline (553.923 us; speedup 1.0000x reference)
//
#include <hip/hip_runtime.h>

// TankModel: B independent rows, each a sequential nonlinear 4-tank scan over
// T steps. Latency/issue-bound: 8192 rows = 128 waves on 1024 SIMDs, so wall
// time = per-wave sequential cost (~34 inst/step x 2 cyc). Round-1 lost 3x to
// exposed load latency (compiler sank the register prefetch). This version
// stages P through LDS with a deterministic 1-tile software pipeline:
//   - coalesced cooperative float4 loads of tile k+1 into regs during compute
//     of tile k (loads in flight ~4300 cyc, fully hidden; barriers pin the
//     scheduling region so they can't be sunk)
//   - LDS row stride 65 floats -> every access pattern is <=2-way bank
//     aliasing (free on gfx950)
//   - uniform full-T loop; t<len output mask via cndmask (wave runs to
//     max-lane length regardless, so per-lane early exit buys nothing)

#define TILE   64
#define LSTRIDE 65

__global__ __launch_bounds__(64)
void tank_kernel(
    const float* __restrict__ P,
    const int*   __restrict__ lengths,
    const float* __restrict__ S0,
    const float* __restrict__ AreaP,
    const float* __restrict__ p_r1h1, const float* __restrict__ p_r1h2,
    const float* __restrict__ p_h1h1, const float* __restrict__ p_h1h2,
    const float* __restrict__ p_ri2,  const float* __restrict__ p_ro2,
    const float* __restrict__ p_h2,
    const float* __restrict__ p_ri3,  const float* __restrict__ p_ro3,
    const float* __restrict__ p_h3,
    const float* __restrict__ p_ri4,  const float* __restrict__ p_ro4,
    float* __restrict__ Out,
    int B, int T)
{
    __shared__ float sP[TILE * LSTRIDE];

    const int tid  = threadIdx.x;
    const int row0 = blockIdx.x * 64;
    const int row  = row0 + tid;
    const bool live = (row < B);
    const int rowc = live ? row : (B - 1);

    // Uniform scalar parameters (folded: max(r*(w-h+p),0) == max(fma(r,w+p,-r*h),0))
    const float r1h1 = p_r1h1[0], r1h2 = p_r1h2[0];
    const float k1 = -r1h1 * p_h1h1[0];
    const float k2 = -r1h2 * p_h1h2[0];
    const float ri2 = p_ri2[0];
    const float ro2 = p_ro2[0];
    const float k3 = -ro2 * p_h2[0];
    const float ri3 = p_ri3[0];
    const float ro3 = p_ro3[0];
    const float k4 = -ro3 * p_h3[0];
    const float ri4 = p_ri4[0];
    const float ro4 = p_ro4[0];
    const float scale = AreaP[0] * (1.0f / 3.6f);

    float w1 = S0[0], w2 = S0[1], w3 = S0[2], w4 = S0[3];

    int len = lengths[rowc];
    if (len > T) len = T;
    if (len < 0) len = 0;

    // Cooperative staging map: iter k covers rows 4k+(tid>>4), 16 consecutive
    // lanes read 256 B contiguous (4 segments per wave-instruction).
    const int sr = tid >> 4;        // row offset within group-of-4
    const int sc = (tid & 15) * 4;  // float column within the 64-step tile
    int srow = row0 + sr;
    if (srow >= B) srow = B - 1;    // clamped base row for staging (4k added per iter is still <B when B%64==0; general clamp below)
    const float* Pst = P + (size_t)srow * T + sc;

    const int ntiles = T / TILE;    // T % 64 == 0 for this problem (T=4096)

    float4 pre[16];
    // Prefetch tile 0
    #pragma unroll
    for (int k = 0; k < 16; ++k) {
        int rr = row0 + 4 * k + sr;
        const float* src = (rr < B) ? (P + (size_t)rr * T + sc) : (P + (size_t)(B - 1) * T + sc);
        pre[k] = *reinterpret_cast<const float4*>(src);
    }
    (void)Pst;

#define STEP(pp, tot) do {                                  \
        float t1 = w1 + (pp);                               \
        float a1 = fmaxf(fmaf(r1h1, t1, k1), 0.0f);         \
        float a2 = fmaxf(fmaf(r1h2, t1, k2), 0.0f);         \
        float o12 = fmaxf(ri2 * t1, 0.0f);                  \
        float of1 = a1 + a2;                                \
        w1 = t1 - of1 - o12;                                \
        float t2 = w2 + o12;                                \
        float of2 = fmaxf(fmaf(ro2, t2, k3), 0.0f);         \
        float o23 = fmaxf(ri3 * t2, 0.0f);                  \
        w2 = t2 - of2 - o23;                                \
        float t3 = w3 + o23;                                \
        float of3 = fmaxf(fmaf(ro3, t3, k4), 0.0f);         \
        float o34 = fmaxf(ri4 * t3, 0.0f);                  \
        w3 = t3 - of3 - o34;                                \
        float t4v = w4 + o34;                               \
        float of4 = fmaxf(ro4 * t4v, 0.0f);                 \
        w4 = t4v - of4;                                     \
        (tot) = ((of1 + of2) + (of3 + of4)) * scale;        \
    } while (0)

    for (int tile = 0; tile < ntiles; ++tile) {
        __syncthreads();   // previous tile's LDS reads complete before overwrite
        // Dump prefetched tile into LDS (row-major, stride 65 -> <=2-way banks)
        #pragma unroll
        for (int k = 0; k < 16; ++k) {
            int r = 4 * k + sr;
            float4 v = pre[k];
            float* d = &sP[r * LSTRIDE + sc];
            d[0] = v.x; d[1] = v.y; d[2] = v.z; d[3] = v.w;
        }
        __syncthreads();   // staging visible to all lanes

        // Issue prefetch for next tile NOW — in flight during the 64-step compute.
        if (tile + 1 < ntiles) {
            const int toff = (tile + 1) * TILE;
            #pragma unroll
            for (int k = 0; k < 16; ++k) {
                int rr = row0 + 4 * k + sr;
                const float* src = (rr < B) ? (P + (size_t)rr * T + sc + toff)
                                            : (P + (size_t)(B - 1) * T + sc + toff);
                pre[k] = *reinterpret_cast<const float4*>(src);
            }
        }

        // Compute 64 steps for this lane's row from LDS.
        const float* myP = &sP[tid * LSTRIDE];
        const int lrel = len - tile * TILE;   // valid steps within this tile
        float4* Ov = reinterpret_cast<float4*>(Out + (size_t)rowc * T + tile * TILE);

        #pragma unroll 4
        for (int q = 0; q < TILE / 4; ++q) {
            float4 o;
            {
                float tot; STEP(myP[4 * q + 0], tot);
                o.x = (4 * q + 0 < lrel) ? tot : 0.0f;
            }
            {
                float tot; STEP(myP[4 * q + 1], tot);
                o.y = (4 * q + 1 < lrel) ? tot : 0.0f;
            }
            {
                float tot; STEP(myP[4 * q + 2], tot);
                o.z = (4 * q + 2 < lrel) ? tot : 0.0f;
            }
            {
                float tot; STEP(myP[4 * q + 3], tot);
                o.w = (4 * q + 3 < lrel) ? tot : 0.0f;
            }
            if (live) Ov[q] = o;
        }
    }
#undef STEP
}

extern "C" void kernel_launch(void* const* d_in, const int* in_sizes, int n_in,
                              void* d_out, int out_size, void* d_ws, size_t ws_size,
                              hipStream_t stream) {
    const float* P        = (const float*)d_in[0];
    const int*   lengths  = (const int*)d_in[1];
    const float* S0       = (const float*)d_in[2];
    const float* Area     = (const float*)d_in[3];
    // d_in[4] = baseflow (unused by forward)
    const float* r1h1 = (const float*)d_in[5];
    const float* r1h2 = (const float*)d_in[6];
    const float* h1h1 = (const float*)d_in[7];
    const float* h1h2 = (const float*)d_in[8];
    const float* ri2  = (const float*)d_in[9];
    const float* ro2  = (const float*)d_in[10];
    const float* h2   = (const float*)d_in[11];
    const float* ri3  = (const float*)d_in[12];
    const float* ro3  = (const float*)d_in[13];
    const float* h3   = (const float*)d_in[14];
    const float* ri4  = (const float*)d_in[15];
    const float* ro4  = (const float*)d_in[16];
    float* out = (float*)d_out;

    const int B = in_sizes[1];
    const int T = in_sizes[0] / B;

    dim3 block(64);
    dim3 grid((B + 63) / 64);
    hipLaunchKernelGGL(tank_kernel, grid, block, 0, stream,
                       P, lengths, S0, Area,
                       r1h1, r1h2, h1h1, h1h2,
                       ri2, ro2, h2, ri3, ro3, h3, ri4, ro4,
                       out, B, T);
}

// Round 3
// 492.549 us; speedup vs baseline: 1.1246x; 1.1246x over previous
//
#include <hip/hip_runtime.h>
#include <stdint.h>

// TankModel: B=8192 independent rows, sequential nonlinear 4-tank scan over
// T=4096 steps. 128 waves on 1024 SIMDs -> pure exposed-latency regime; wall
// time = per-wave sequential cost. Design rules here:
//   - ALL global traffic is wave-wide and async: global_load_lds(width=16)
//     staging (zero VGPR cost -> compiler cannot sink it), double-buffered,
//     issued one full tile (~4000 cyc) before the single per-tile barrier.
//   - LDS tile uses XOR swizzle (phys float4-slot = c4 ^ (row&15)): satisfies
//     global_load_lds' lane-contiguous destination AND gives minimum 8-phase
//     ds_read_b128 per-lane row reads (unpadded stride-64 would be 64-way).
//   - per 4 steps: ONE ds_read_b128 issued 2 groups (~500 cyc) early.
//   - outputs staged in an LDS tile, cooperatively stored as full-sector
//     global_store_dwordx4 (fixes round-2's 3.7x write amplification).
//   - STEP uses max(r*x,0)==r*max(x,0) (rates>0): 31 VALU/step, recurrence
//     chains ~6 ops/tank.

#define GLOBAL_AS __attribute__((address_space(1)))
#define LDS_AS    __attribute__((address_space(3)))

__device__ __forceinline__ void async_ld16(const float* gp, float* lds_base) {
    // HW semantics: lane i writes lds_base + i*16 bytes; gp is per-lane.
    __builtin_amdgcn_global_load_lds((const GLOBAL_AS void*)gp,
                                     (LDS_AS void*)lds_base, 16, 0, 0);
}

#define TILE_T 64          // time steps per tile
// tile in LDS: 64 rows x 16 float4 slots, phys slot = c4 ^ (row & 15)

__global__ __launch_bounds__(64)
void tank_kernel(
    const float* __restrict__ P,
    const int*   __restrict__ lengths,
    const float* __restrict__ S0,
    const float* __restrict__ AreaP,
    const float* __restrict__ p_r1h1, const float* __restrict__ p_r1h2,
    const float* __restrict__ p_h1h1, const float* __restrict__ p_h1h2,
    const float* __restrict__ p_ri2,  const float* __restrict__ p_ro2,
    const float* __restrict__ p_h2,
    const float* __restrict__ p_ri3,  const float* __restrict__ p_ro3,
    const float* __restrict__ p_h3,
    const float* __restrict__ p_ri4,  const float* __restrict__ p_ro4,
    float* __restrict__ Out,
    int B, int T)
{
    __shared__ float inbuf[2][TILE_T * TILE_T];   // 2 x 16 KB
    __shared__ float outbuf[2][TILE_T * TILE_T];  // 2 x 16 KB

    const int tid  = threadIdx.x;
    const int row0 = blockIdx.x * 64;
    const int myrow = row0 + tid;
    const bool live = (myrow < B);
    const int rowc = live ? myrow : (B - 1);

    // Uniform params -> SGPRs. Folded constants.
    const float r1h1 = p_r1h1[0], r1h2 = p_r1h2[0];
    const float k1 = -r1h1 * p_h1h1[0];
    const float k2 = -r1h2 * p_h1h2[0];
    const float ri2 = p_ri2[0];
    const float ro2 = p_ro2[0];
    const float k3 = -ro2 * p_h2[0];
    const float ri3 = p_ri3[0];
    const float ro3 = p_ro3[0];
    const float k4 = -ro3 * p_h3[0];
    const float ri4 = p_ri4[0];
    const float ro4 = p_ro4[0];
    const float scale = AreaP[0] * (1.0f / 3.6f);

    float w1 = S0[0], w2 = S0[1], w3 = S0[2], w4 = S0[3];

    int len = lengths[rowc];
    if (len > T) len = T;
    if (len < 0) len = 0;

    const int sr = tid >> 4;   // staging row-subgroup 0..3
    const int j  = tid & 15;   // staging phys slot / my read swizzle
    const int sw = j;
    const int ntiles = T / TILE_T;   // T % 64 == 0 (T=4096)

    // ---- stage tile 0 into inbuf[0] (async, drained by first barrier) ----
    #pragma unroll
    for (int k = 0; k < 16; ++k) {
        int r  = 4 * k + sr;
        int rg = row0 + r; if (rg >= B) rg = B - 1;
        int c4 = j ^ (r & 15);
        async_ld16(P + (size_t)rg * T + 4 * c4, &inbuf[0][k * 256]);
    }

#define STEP(pp, tot) do {                                  \
        float t1 = w1 + (pp);                               \
        float a1 = fmaxf(fmaf(r1h1, t1, k1), 0.0f);         \
        float a2 = fmaxf(fmaf(r1h2, t1, k2), 0.0f);         \
        float m1 = fmaxf(t1, 0.0f);                         \
        float of1 = a1 + a2;                                \
        float s1 = t1 - of1;                                \
        w1 = fmaf(-ri2, m1, s1);                            \
        float t2 = fmaf(ri2, m1, w2);                       \
        float of2 = fmaxf(fmaf(ro2, t2, k3), 0.0f);         \
        float m2 = fmaxf(t2, 0.0f);                         \
        float s2 = t2 - of2;                                \
        w2 = fmaf(-ri3, m2, s2);                            \
        float t3 = fmaf(ri3, m2, w3);                       \
        float of3 = fmaxf(fmaf(ro3, t3, k4), 0.0f);         \
        float m3 = fmaxf(t3, 0.0f);                         \
        float s3 = t3 - of3;                                \
        w3 = fmaf(-ri4, m3, s3);                            \
        float t4 = fmaf(ri4, m3, w4);                       \
        float m4 = fmaxf(t4, 0.0f);                         \
        float of4 = ro4 * m4;                               \
        w4 = t4 - of4;                                      \
        (tot) = ((of1 + of2) + (of3 + of4)) * scale;        \
    } while (0)

    for (int tile = 0; tile < ntiles; ++tile) {
        // ONE barrier per tile: drains (a) prev compute's outbuf ds_writes,
        // (b) the stage loads issued a full tile ago, (c) prev coop stores.
        __syncthreads();

        // ---- cooperative store of previous tile's outputs (async-ish:
        //      stores stay in flight until next barrier) ----
        if (tile > 0) {
            const float4* ob = (const float4*)outbuf[(tile - 1) & 1];
            const int pcol = (tile - 1) * TILE_T;
            #pragma unroll
            for (int k = 0; k < 16; ++k) {
                int r  = 4 * k + sr;
                int rg = row0 + r;
                int c4 = j ^ (r & 15);
                float4 v = ob[k * 64 + tid];
                if (rg < B)
                    *reinterpret_cast<float4*>(Out + (size_t)rg * T + pcol + 4 * c4) = v;
            }
        }

        // ---- stage next tile (in flight during this tile's compute) ----
        if (tile + 1 < ntiles) {
            const int ncol = (tile + 1) * TILE_T;
            float* dst = inbuf[(tile + 1) & 1];
            #pragma unroll
            for (int k = 0; k < 16; ++k) {
                int r  = 4 * k + sr;
                int rg = row0 + r; if (rg >= B) rg = B - 1;
                int c4 = j ^ (r & 15);
                async_ld16(P + (size_t)rg * T + ncol + 4 * c4, dst + k * 256);
            }
        }

        // ---- compute 64 steps from inbuf[tile&1], write outbuf[tile&1] ----
        const float4* inb = (const float4*)inbuf[tile & 1];
        float4*       ob  = (float4*)outbuf[tile & 1];
        const int base16 = tid * 16;
        const int lrel = len - tile * TILE_T;

        float4 cur = inb[base16 + (0 ^ sw)];
        float4 nxt = inb[base16 + (1 ^ sw)];
        #pragma unroll 4
        for (int q = 0; q < 16; ++q) {
            float4 after = inb[base16 + (((q + 2) & 15) ^ sw)]; // 2 groups ahead
            float4 o;
            float tot;
            STEP(cur.x, tot); o.x = (4 * q + 0 < lrel) ? tot : 0.0f;
            STEP(cur.y, tot); o.y = (4 * q + 1 < lrel) ? tot : 0.0f;
            STEP(cur.z, tot); o.z = (4 * q + 2 < lrel) ? tot : 0.0f;
            STEP(cur.w, tot); o.w = (4 * q + 3 < lrel) ? tot : 0.0f;
            ob[base16 + (q ^ sw)] = o;
            cur = nxt; nxt = after;
        }
    }
#undef STEP

    // ---- epilogue: store last tile's outputs ----
    __syncthreads();
    {
        const float4* ob = (const float4*)outbuf[(ntiles - 1) & 1];
        const int pcol = (ntiles - 1) * TILE_T;
        #pragma unroll
        for (int k = 0; k < 16; ++k) {
            int r  = 4 * k + sr;
            int rg = row0 + r;
            int c4 = j ^ (r & 15);
            float4 v = ob[k * 64 + tid];
            if (rg < B)
                *reinterpret_cast<float4*>(Out + (size_t)rg * T + pcol + 4 * c4) = v;
        }
    }
}

extern "C" void kernel_launch(void* const* d_in, const int* in_sizes, int n_in,
                              void* d_out, int out_size, void* d_ws, size_t ws_size,
                              hipStream_t stream) {
    const float* P        = (const float*)d_in[0];
    const int*   lengths  = (const int*)d_in[1];
    const float* S0       = (const float*)d_in[2];
    const float* Area     = (const float*)d_in[3];
    // d_in[4] = baseflow (unused by forward)
    const float* r1h1 = (const float*)d_in[5];
    const float* r1h2 = (const float*)d_in[6];
    const float* h1h1 = (const float*)d_in[7];
    const float* h1h2 = (const float*)d_in[8];
    const float* ri2  = (const float*)d_in[9];
    const float* ro2  = (const float*)d_in[10];
    const float* h2   = (const float*)d_in[11];
    const float* ri3  = (const float*)d_in[12];
    const float* ro3  = (const float*)d_in[13];
    const float* h3   = (const float*)d_in[14];
    const float* ri4  = (const float*)d_in[15];
    const float* ro4  = (const float*)d_in[16];
    float* out = (float*)d_out;

    const int B = in_sizes[1];
    const int T = in_sizes[0] / B;

    dim3 block(64);
    dim3 grid((B + 63) / 64);
    hipLaunchKernelGGL(tank_kernel, grid, block, 0, stream,
                       P, lengths, S0, Area,
                       r1h1, r1h2, h1h1, h1h2,
                       ri2, ro2, h2, ri3, ro3, h3, ri4, ro4,
                       out, B, T);
}

// Round 4
// 487.584 us; speedup vs baseline: 1.1361x; 1.0102x over previous
//
#include <hip/hip_runtime.h>
#include <stdint.h>

// TankModel: B=8192 independent chains, sequential nonlinear 4-tank scan,
// T=4096. One chain per lane gives only 128 waves on 1024 SIMDs -> per-wave
// issue cadence IS the wall time (r3: 176 cyc/step vs ~60 floor, VALUBusy 9%).
// This version splits each chain across 4 lanes (tank j -> lane 4g+j) in a
// systolic pipeline: lane j processes time t=i-j at iteration i; inter-tank
// flow and the running outflow-sum move lane j-1 -> j via DPP row_shr:1
// (VALU-speed cross-lane, no LDS). 4x the waves (512), ~4x fewer
// instructions per chain-step per wave.
//   - all 4 tanks share one step form; per-lane constants select the tank
//     (tank1's 2nd outlet has rate=k=0 on lanes 1-3; tank4 has ri_next=0).
//   - warm-up: w frozen until i >= lane_role (cndmask; exact thereafter).
//   - P staged like r3: coalesced reg loads one tile ahead -> XOR-swizzled
//     LDS (conflict-free broadcast ds_read_b128: 4 lanes/group same addr).
//   - lane3 accumulates 4 outputs -> ds_write_b128 into triple-buffered
//     out-tile, coop-stored 2 tiles later (full-sector global writes).

__device__ __forceinline__ float dpp_shr1(float x) {
    int xi = __builtin_bit_cast(int, x);
    int r = __builtin_amdgcn_update_dpp(xi, xi, 0x111 /*row_shr:1*/, 0xF, 0xF, false);
    return __builtin_bit_cast(float, r);
}

__global__ __launch_bounds__(64)
void tank_kernel(
    const float* __restrict__ P,
    const int*   __restrict__ lengths,
    const float* __restrict__ S0,
    const float* __restrict__ AreaP,
    const float* __restrict__ p_r1h1, const float* __restrict__ p_r1h2,
    const float* __restrict__ p_h1h1, const float* __restrict__ p_h1h2,
    const float* __restrict__ p_ri2,  const float* __restrict__ p_ro2,
    const float* __restrict__ p_h2,
    const float* __restrict__ p_ri3,  const float* __restrict__ p_ro3,
    const float* __restrict__ p_h3,
    const float* __restrict__ p_ri4,  const float* __restrict__ p_ro4,
    float* __restrict__ Out,
    int B, int T)
{
    __shared__ float4 inbuf[2 * 256];   // 2 x [16 rows][16 float4], XOR swizzle
    __shared__ float4 outbuf[3 * 256];  // 3 x [16 rows][16 float4]

    const int tid = threadIdx.x;
    const int g   = tid >> 2;          // group = row within block (16 rows)
    const int k   = tid & 3;           // tank role 0..3
    const int row = blockIdx.x * 16 + g;
    const int rowc = (row < B) ? row : (B - 1);
    const bool is0 = (k == 0);
    const bool is3 = (k == 3);
    const int klane = k;

    // Uniform params.
    const float v_r1h1 = p_r1h1[0], v_r1h2 = p_r1h2[0];
    const float v_h11 = p_h1h1[0], v_h12 = p_h1h2[0];
    const float v_ri2 = p_ri2[0], v_ro2 = p_ro2[0], v_h2 = p_h2[0];
    const float v_ri3 = p_ri3[0], v_ro3 = p_ro3[0], v_h3 = p_h3[0];
    const float v_ri4 = p_ri4[0], v_ro4 = p_ro4[0];
    const float scale = AreaP[0] * (1.0f / 3.6f);

    // Per-lane tank constants.
    float rA = v_ro4, kA = 0.0f, rB = 0.0f, kB = 0.0f, riN = 0.0f;
    if (k == 0) { rA = v_r1h1; kA = -v_r1h1 * v_h11; rB = v_r1h2; kB = -v_r1h2 * v_h12; riN = v_ri2; }
    else if (k == 1) { rA = v_ro2; kA = -v_ro2 * v_h2; riN = v_ri3; }
    else if (k == 2) { rA = v_ro3; kA = -v_ro3 * v_h3; riN = v_ri4; }

    float w = (k == 0) ? S0[0] : (k == 1) ? S0[1] : (k == 2) ? S0[2] : S0[3];

    int len = lengths[rowc];
    if (len > T) len = T;
    if (len < 0) len = 0;

    float flow = 0.0f, part = 0.0f;
    float4 o = make_float4(0.0f, 0.0f, 0.0f, 0.0f);

    const int ntiles = T / 64;   // 64 for T=4096

// One systolic iteration. ii = scalar iteration index; lane role j computes
// time t = ii - j. Order matters: dpp reads BEFORE flow/part overwritten.
#define STEP(pin, ii, ocomp) do {                               \
        float fin  = dpp_shr1(flow);                            \
        float prin = dpp_shr1(part);                            \
        float in   = is0 ? (pin) : fin;                         \
        float pb   = is0 ? 0.0f : prin;                         \
        float t    = w + in;                                    \
        float a1   = fmaxf(fmaf(rA, t, kA), 0.0f);              \
        float a2   = fmaxf(fmaf(rB, t, kB), 0.0f);              \
        float mm   = fmaxf(t, 0.0f);                            \
        float fl   = riN * mm;                                  \
        float os   = a1 + a2;                                   \
        float wn   = t - os - fl;                               \
        w = ((ii) >= klane) ? wn : w;  /* warm-up freeze */     \
        flow = fl;                                              \
        part = pb + os;                                         \
        float tot = part * scale;                               \
        (ocomp) = (((ii) - 3) < len) ? tot : 0.0f;              \
    } while (0)

    // Stage tile 0 into regs (coalesced: 4 lanes of a group read 64B).
    float4 st[4];
    {
        const float* src = P + (size_t)rowc * T;
        #pragma unroll
        for (int r = 0; r < 4; ++r)
            st[r] = *reinterpret_cast<const float4*>(src + (4 * r + k) * 4);
    }

    for (int m = 0; m < ntiles; ++m) {
        // 1) staged regs -> LDS (swizzled: slot q^g for row g, q = 4r+k)
        float4* ib = inbuf + (m & 1) * 256;
        #pragma unroll
        for (int r = 0; r < 4; ++r)
            ib[g * 16 + ((4 * r + k) ^ g)] = st[r];

        // 2) single per-tile barrier (single wave per block: this is just the
        //    waitcnt drain; prev tile's stores/loads are a full tile old).
        __syncthreads();

        // 3) coop-store out-tile m-2 (fire-and-forget; drains at next barrier)
        if (m >= 2) {
            const float4* ob = outbuf + ((m - 2) % 3) * 256;
            const int col0 = (m - 2) * 64;
            #pragma unroll
            for (int r = 0; r < 4; ++r) {
                float4 v = ob[g * 16 + ((4 * r + k) ^ g)];
                if (row < B)
                    *reinterpret_cast<float4*>(Out + (size_t)row * T + col0 + (4 * r + k) * 4) = v;
            }
        }

        // 4) global loads for tile m+1 (in flight across the whole compute)
        if (m + 1 < ntiles) {
            const float* src = P + (size_t)rowc * T + (m + 1) * 64;
            #pragma unroll
            for (int r = 0; r < 4; ++r)
                st[r] = *reinterpret_cast<const float4*>(src + (4 * r + k) * 4);
        }

        // 5) 64 systolic iterations. Group g broadcast-reads its p block
        //    (4 lanes same addr = free; 16 groups hit distinct bank-quads).
        const int i0 = m * 64;
        float4 c0 = ib[g * 16 + (0 ^ g)];
        float4 c1 = ib[g * 16 + (1 ^ g)];
        #pragma unroll 4
        for (int j4 = 0; j4 < 16; ++j4) {
            float4 c2 = ib[g * 16 + (((j4 + 2) & 15) ^ g)];
            const int i = i0 + 4 * j4;
            // lane3's time t3 = i-3; component c = (t3&3): y,z,w then flush, x
            STEP(c0.x, i + 0, o.y);
            STEP(c0.y, i + 1, o.z);
            STEP(c0.z, i + 2, o.w);
            const int b = (i0 >> 2) + j4 - 1;   // completed output block
            if (b >= 0 && is3) {
                float4* obp = outbuf + ((b >> 4) % 3) * 256;
                obp[g * 16 + ((b & 15) ^ g)] = o;
            }
            STEP(c0.w, i + 3, o.x);
            c0 = c1; c1 = c2;
        }
    }

    // Drain: 3 iters so lane3 reaches t = T-1. p value irrelevant (masked).
    STEP(0.0f, T + 0, o.y);
    STEP(0.0f, T + 1, o.z);
    STEP(0.0f, T + 2, o.w);
    {
        const int lastb = (T >> 2) - 1;
        if (is3) {
            float4* obp = outbuf + ((lastb >> 4) % 3) * 256;
            obp[g * 16 + ((lastb & 15) ^ g)] = o;
        }
    }
#undef STEP

    // Epilogue: store out-tiles ntiles-2, ntiles-1.
    __syncthreads();
    #pragma unroll
    for (int e = 0; e < 2; ++e) {
        const int mt = ntiles - 2 + e;
        const float4* ob = outbuf + (mt % 3) * 256;
        const int col0 = mt * 64;
        #pragma unroll
        for (int r = 0; r < 4; ++r) {
            float4 v = ob[g * 16 + ((4 * r + k) ^ g)];
            if (row < B)
                *reinterpret_cast<float4*>(Out + (size_t)row * T + col0 + (4 * r + k) * 4) = v;
        }
    }
}

extern "C" void kernel_launch(void* const* d_in, const int* in_sizes, int n_in,
                              void* d_out, int out_size, void* d_ws, size_t ws_size,
                              hipStream_t stream) {
    const float* P        = (const float*)d_in[0];
    const int*   lengths  = (const int*)d_in[1];
    const float* S0       = (const float*)d_in[2];
    const float* Area     = (const float*)d_in[3];
    // d_in[4] = baseflow (unused by forward)
    const float* r1h1 = (const float*)d_in[5];
    const float* r1h2 = (const float*)d_in[6];
    const float* h1h1 = (const float*)d_in[7];
    const float* h1h2 = (const float*)d_in[8];
    const float* ri2  = (const float*)d_in[9];
    const float* ro2  = (const float*)d_in[10];
    const float* h2   = (const float*)d_in[11];
    const float* ri3  = (const float*)d_in[12];
    const float* ro3  = (const float*)d_in[13];
    const float* h3   = (const float*)d_in[14];
    const float* ri4  = (const float*)d_in[15];
    const float* ro4  = (const float*)d_in[16];
    float* out = (float*)d_out;

    const int B = in_sizes[1];
    const int T = in_sizes[0] / B;

    dim3 block(64);
    dim3 grid((B + 15) / 16);   // 16 chains per block (4 lanes/chain)
    hipLaunchKernelGGL(tank_kernel, grid, block, 0, stream,
                       P, lengths, S0, Area,
                       r1h1, r1h2, h1h1, h1h2,
                       ri2, ro2, h2, ri3, ro3, h3, ri4, ro4,
                       out, B, T);
}